// Round 16
// baseline (773.590 us; speedup 1.0000x reference)
//
#include <hip/hip_runtime.h>
#include <math.h>

// Problem constants
#define NB 8
#define SEQ 1024
#define DM 512
#define NH 8
#define HDIM 64
#define DFF 2048
#define NLAYER 4
#define NTOK (NB * SEQ)   // 8192
#define QKVD 1536         // fused q|k|v row width

typedef __attribute__((ext_vector_type(8))) short bf16x8;
typedef __attribute__((ext_vector_type(4))) float f32x4;

__device__ __forceinline__ ushort f2bf(float f) {
    union { float f; unsigned u; } v; v.f = f;
    unsigned r = (v.u + 0x7FFF + ((v.u >> 16) & 1)) >> 16;  // RNE
    return (ushort)r;
}

// async global->LDS, 16B per lane
__device__ __forceinline__ void async16(const void* g, void* l) {
    __builtin_amdgcn_global_load_lds(
        (const __attribute__((address_space(1))) unsigned int*)g,
        (__attribute__((address_space(3))) unsigned int*)l, 16, 0, 0);
}

// ---------------------------------------------------------------------------
// Positional encoding add
// ---------------------------------------------------------------------------
__global__ __launch_bounds__(256) void add_pos_kernel(const float* __restrict__ x,
                                                      float* __restrict__ out) {
    int idx4 = blockIdx.x * blockDim.x + threadIdx.x;
    int base = idx4 * 4;
    int d = base & (DM - 1);
    int s = (base >> 9) & (SEQ - 1);
    float4 v = *(const float4*)&x[base];
    float r[4] = {v.x, v.y, v.z, v.w};
#pragma unroll
    for (int i = 0; i < 4; i++) {
        int dd = d + i;
        float pe;
        if (dd < 256) {
            float inv = powf(10000.0f, 2.0f * (float)dd / 512.0f);
            pe = sinf((float)s / inv);
        } else {
            float inv = powf(10000.0f, 2.0f * (float)(dd - 256) / 512.0f);
            pe = cosf((float)s / inv);
        }
        r[i] += pe;
    }
    *(float4*)&out[base] = make_float4(r[0], r[1], r[2], r[3]);
}

// ---------------------------------------------------------------------------
// Merged weight convert+transpose: ALL 6 weight tensors in ONE dispatch.
// Flat grid x = 3072 blocks/layer (segment table below), z = layer.
// ---------------------------------------------------------------------------
__global__ __launch_bounds__(256) void wtrans_all(
    const float* __restrict__ Wq, const float* __restrict__ Wk,
    const float* __restrict__ Wv, const float* __restrict__ Wo,
    const float* __restrict__ W1, const float* __restrict__ W2,
    ushort* __restrict__ WqkvT, ushort* __restrict__ WoT,
    ushort* __restrict__ W1T, ushort* __restrict__ W2T) {
    __shared__ float tile[32][36];
    const int l = blockIdx.z;
    const int bid = blockIdx.x;
    const float* src; ushort* dst;
    int K, N, rowOff, stride, t, nxk;
    if (bid < 1024) {
        int seg = bid >> 8; t = bid & 255;
        K = 512; N = 512; nxk = 16;
        if (seg == 0)      { src = Wq; dst = WqkvT; rowOff = 0;    stride = 786432; }
        else if (seg == 1) { src = Wk; dst = WqkvT; rowOff = 512;  stride = 786432; }
        else if (seg == 2) { src = Wv; dst = WqkvT; rowOff = 1024; stride = 786432; }
        else               { src = Wo; dst = WoT;   rowOff = 0;    stride = 262144; }
    } else if (bid < 2048) {
        t = bid - 1024; K = 512; N = 2048; nxk = 64;
        src = W1; dst = W1T; rowOff = 0; stride = 1048576;
    } else {
        t = bid - 2048; K = 2048; N = 512; nxk = 16;
        src = W2; dst = W2T; rowOff = 0; stride = 1048576;
    }
    const int bx = t % nxk, by = t / nxk;
    const int kb = by * 32, nb = bx * 32;
    const float* s = src + (size_t)l * K * N;
    ushort* d = dst + (size_t)l * stride;
    int r = threadIdx.x >> 3, c4 = (threadIdx.x & 7) * 4;
    float4 v = *(const float4*)&s[(size_t)(kb + r) * N + nb + c4];
    *(float4*)&tile[r][c4] = v;
    __syncthreads();
    ushort4 o;
    o.x = f2bf(tile[c4 + 0][r]);
    o.y = f2bf(tile[c4 + 1][r]);
    o.z = f2bf(tile[c4 + 2][r]);
    o.w = f2bf(tile[c4 + 3][r]);
    *(ushort4*)&d[(size_t)(rowOff + nb + r) * K + kb + c4] = o;
}

// ---------------------------------------------------------------------------
// LayerNorm fp32 in -> bf16 out. One wave per row, 4 rows/block.
// ---------------------------------------------------------------------------
__global__ __launch_bounds__(256) void ln_kernel(const float* __restrict__ x,
                                                 const float* __restrict__ g,
                                                 const float* __restrict__ bta,
                                                 ushort* __restrict__ out) {
    int w = threadIdx.x >> 6;
    int lane = threadIdx.x & 63;
    size_t row = (size_t)blockIdx.x * 4 + w;
    const float* xr = x + row * DM;
    float4 v0 = *(const float4*)&xr[lane * 4];
    float4 v1 = *(const float4*)&xr[256 + lane * 4];
    float sum = v0.x + v0.y + v0.z + v0.w + v1.x + v1.y + v1.z + v1.w;
#pragma unroll
    for (int off = 32; off > 0; off >>= 1) sum += __shfl_xor(sum, off, 64);
    float mu = sum * (1.0f / 512.0f);
    float d0[8] = {v0.x - mu, v0.y - mu, v0.z - mu, v0.w - mu,
                   v1.x - mu, v1.y - mu, v1.z - mu, v1.w - mu};
    float sq = 0.0f;
#pragma unroll
    for (int i = 0; i < 8; i++) sq = fmaf(d0[i], d0[i], sq);
#pragma unroll
    for (int off = 32; off > 0; off >>= 1) sq += __shfl_xor(sq, off, 64);
    float rs = rsqrtf(sq * (1.0f / 512.0f) + 1e-3f);
    float4 g0 = *(const float4*)&g[lane * 4];
    float4 g1 = *(const float4*)&g[256 + lane * 4];
    float4 b0 = *(const float4*)&bta[lane * 4];
    float4 b1 = *(const float4*)&bta[256 + lane * 4];
    ushort* orow = out + row * DM;
    ushort4 o0, o1;
    o0.x = f2bf(fmaf(d0[0] * rs, g0.x, b0.x));
    o0.y = f2bf(fmaf(d0[1] * rs, g0.y, b0.y));
    o0.z = f2bf(fmaf(d0[2] * rs, g0.z, b0.z));
    o0.w = f2bf(fmaf(d0[3] * rs, g0.w, b0.w));
    o1.x = f2bf(fmaf(d0[4] * rs, g1.x, b1.x));
    o1.y = f2bf(fmaf(d0[5] * rs, g1.y, b1.y));
    o1.z = f2bf(fmaf(d0[6] * rs, g1.z, b1.z));
    o1.w = f2bf(fmaf(d0[7] * rs, g1.w, b1.w));
    *(ushort4*)&orow[lane * 4] = o0;
    *(ushort4*)&orow[256 + lane * 4] = o1;
}

// ---------------------------------------------------------------------------
// bf16 MFMA GEMM, BM x BN tile, BK = 32*KH, 8 waves (4x2), 512 threads,
// T1 bijective XCD swizzle (requires gridDim.y % 8 == 0).
// NBUF=2: r5 2-phase double-buffer (drain-to-zero barrier) — proven optimum
//         at 3-4 blocks/CU for QKV/FF1 (r12/r14).
// NBUF=3: counted-vmcnt ring (T3/T4): prologue stages tiles 0,1; iter t
//         issues stage t+2 into the buffer read at t-1 (safe: those reads
//         are ordered by the lgkmcnt(0) in barrier t-1); the combined asm
//         waits vmcnt(OPS) = only tile t+1's loads, so t+2's prefetch stays
//         in flight across the barrier. Used for proj/FF2 (64x64 KH=2,
//         48KB LDS -> 3 blocks x 8 waves = 24 waves/CU — unlike r6's
//         failed 4-wave variant at ~10 waves/CU).
// Per wave: (BM/4) x (BN/2) output = FM x FN 16x16 frags, FM=BM/64, FN=BN/32.
// MODE: 0 = bf16 store; 1 = fp32 +=; 2 = bias+relu -> bf16; 3 = bias + fp32 +=
//       5 = QKV fused: Q/K col-blocks -> bf16 store; V col-blocks (n0>=1024)
//           -> TRANSPOSED ushort4 store to aux = vT[b][c][s]
// ---------------------------------------------------------------------------
template <int BM, int BN, int KH, int MODE, int NBUF = 2>
__global__ __launch_bounds__(512) void gemm_bf16(const ushort* __restrict__ A,
                                                 const ushort* __restrict__ Bt,
                                                 const float* __restrict__ bias,
                                                 void* __restrict__ Cv,
                                                 void* __restrict__ aux,
                                                 int M, int N, int K) {
    static_assert(BM % 64 == 0 && BN % 64 == 0, "tile multiple of 64");
    constexpr int FM = BM / 64;   // frags per wave, rows (wave grid 4x2)
    constexpr int FN = BN / 32;   // frags per wave, cols
    __shared__ __align__(16) ushort As[NBUF][KH * BM * 32];
    __shared__ __align__(16) ushort Bs[NBUF][KH * BN * 32];
    const int tid = threadIdx.x;
    const int lane = tid & 63;
    const int w = tid >> 6;                  // 0..7

    // --- XCD-locality swizzle (bijective for gridDim.y % 8 == 0) ---
    const int nx = gridDim.x;
    int wg = blockIdx.y * nx + blockIdx.x;   // hw linear dispatch id
    int xcd = wg & 7;
    int t0 = wg >> 3;
    int bx = t0 % nx;
    int by = (t0 / nx) * 8 + xcd;            // same-by blocks share xcd
    const int m0 = by * BM, n0 = bx * BN;

    const int wm = (w >> 1) * (BM / 4);      // wave row (0..3)
    const int wn = (w & 1) * (BN / 2);       // wave col (0..1)
    const int fm = lane & 15, fq = lane >> 4;

    f32x4 acc[FM][FN] = {};

    // stage K-tile [kt, kt+32*KH) into LDS buffer buf (async, wave-linear).
    // chunks16 per hf: A = BM*4, B = BN*4 (each 32-elem row = 4 x 16B).
    auto stage = [&](int buf, int kt) {
#pragma unroll
        for (int hf = 0; hf < KH; hf++) {
            constexpr int CA = BM * 4;
            if constexpr (CA >= 512) {
#pragma unroll
                for (int u = 0; u < CA / 512; u++) {
                    int chunk = u * 512 + tid;
                    int row = chunk >> 2, c = chunk & 3;
                    async16(&A[(size_t)(m0 + row) * K + kt + hf * 32 + c * 8],
                            (char*)As[buf] + hf * BM * 64 + chunk * 16);
                }
            } else {
                if (tid < CA) {
                    int chunk = tid;
                    int row = chunk >> 2, c = chunk & 3;
                    async16(&A[(size_t)(m0 + row) * K + kt + hf * 32 + c * 8],
                            (char*)As[buf] + hf * BM * 64 + chunk * 16);
                }
            }
            constexpr int CB = BN * 4;
            if constexpr (CB >= 512) {
#pragma unroll
                for (int u = 0; u < CB / 512; u++) {
                    int chunk = u * 512 + tid;
                    int row = chunk >> 2, c = chunk & 3;
                    async16(&Bt[(size_t)(n0 + row) * K + kt + hf * 32 + c * 8],
                            (char*)Bs[buf] + hf * BN * 64 + chunk * 16);
                }
            } else {
                if (tid < CB) {
                    int chunk = tid;
                    int row = chunk >> 2, c = chunk & 3;
                    async16(&Bt[(size_t)(n0 + row) * K + kt + hf * 32 + c * 8],
                            (char*)Bs[buf] + hf * BN * 64 + chunk * 16);
                }
            }
        }
    };

    // compute one K-step from LDS buffer cur
    auto compute = [&](int cur) {
#pragma unroll
        for (int hf = 0; hf < KH; hf++) {
            bf16x8 af[FM], bfr[FN];
#pragma unroll
            for (int i = 0; i < FM; i++)
                af[i] = *(const bf16x8*)&As[cur][hf * BM * 32 +
                                                 (wm + i * 16 + fm) * 32 + fq * 8];
#pragma unroll
            for (int j = 0; j < FN; j++)
                bfr[j] = *(const bf16x8*)&Bs[cur][hf * BN * 32 +
                                                  (wn + j * 16 + fm) * 32 + fq * 8];
#pragma unroll
            for (int i = 0; i < FM; i++)
#pragma unroll
                for (int j = 0; j < FN; j++)
                    acc[i][j] = __builtin_amdgcn_mfma_f32_16x16x32_bf16(
                        af[i], bfr[j], acc[i][j], 0, 0, 0);
        }
    };

    if constexpr (NBUF == 3) {
        // per-issuing-thread async16 ops in one stage (threads that issue
        // fewer have fewer outstanding -> the wait passes trivially)
        constexpr int AOPS = (BM * 4 >= 512) ? (BM * 4 / 512) : 1;
        constexpr int BOPS = (BN * 4 >= 512) ? (BN * 4 / 512) : 1;
        constexpr int OPS = KH * (AOPS + BOPS);
        const int nsteps = K / (32 * KH);
        stage(0, 0);
        stage(1, 32 * KH);
        // tile0 done (tile1 stays in flight), then barrier
        asm volatile("s_waitcnt vmcnt(%0) lgkmcnt(0)\ns_barrier" :: "i"(OPS) : "memory");
        for (int t = 0; t < nsteps; ++t) {
            const int cur = t % 3;
            if (t + 2 < nsteps) stage((t + 2) % 3, (t + 2) * 32 * KH);
            compute(cur);
            if (t + 1 < nsteps) {
                if (t + 2 < nsteps)
                    asm volatile("s_waitcnt vmcnt(%0) lgkmcnt(0)\ns_barrier"
                                 :: "i"(OPS) : "memory");
                else
                    asm volatile("s_waitcnt vmcnt(0) lgkmcnt(0)\ns_barrier"
                                 ::: "memory");
            }
        }
    } else {
        stage(0, 0);
        __syncthreads();
        int cur = 0;
        for (int kt = 0; kt < K; kt += 32 * KH) {
            if (kt + 32 * KH < K) stage(cur ^ 1, kt + 32 * KH);  // prefetch next
            compute(cur);
            __syncthreads();   // drains prefetch (vmcnt) + ds_reads (lgkmcnt)
            cur ^= 1;
        }
    }

    if constexpr (MODE == 5) {
        if (n0 >= 1024) {
            // V col-block: transposed write to vT[b][c][s]; acc rows are 4
            // consecutive s at fixed c -> one 8B ushort4 store per frag.
            ushort* vT = (ushort*)aux;
            const int b = m0 >> 10;               // BM tiles never cross batch
            const int sl = (m0 & (SEQ - 1)) + wm + fq * 4;
#pragma unroll
            for (int i = 0; i < FM; i++) {
#pragma unroll
                for (int j = 0; j < FN; j++) {
                    int c = n0 - 1024 + wn + j * 16 + fm;
                    ushort4 o;
                    o.x = f2bf(acc[i][j][0]);
                    o.y = f2bf(acc[i][j][1]);
                    o.z = f2bf(acc[i][j][2]);
                    o.w = f2bf(acc[i][j][3]);
                    *(ushort4*)&vT[(size_t)(b * DM + c) * SEQ + sl + i * 16] = o;
                }
            }
        } else {
            // Q/K col-block: normal bf16 store
#pragma unroll
            for (int i = 0; i < FM; i++)
#pragma unroll
                for (int j = 0; j < FN; j++) {
                    int col = n0 + wn + j * 16 + fm;
#pragma unroll
                    for (int r = 0; r < 4; r++) {
                        int row = m0 + wm + i * 16 + fq * 4 + r;
                        ((ushort*)Cv)[(size_t)row * N + col] = f2bf(acc[i][j][r]);
                    }
                }
        }
        return;
    }

#pragma unroll
    for (int i = 0; i < FM; i++) {
#pragma unroll
        for (int j = 0; j < FN; j++) {
            int col = n0 + wn + j * 16 + fm;
#pragma unroll
            for (int r = 0; r < 4; r++) {
                int row = m0 + wm + i * 16 + fq * 4 + r;
                float vv = acc[i][j][r];
                if constexpr (MODE == 0) {
                    ((ushort*)Cv)[(size_t)row * N + col] = f2bf(vv);
                } else if constexpr (MODE == 1) {
                    float* C = (float*)Cv;
                    C[(size_t)row * N + col] += vv;
                } else if constexpr (MODE == 2) {
                    vv += bias[col];
                    vv = fmaxf(vv, 0.0f);
                    ((ushort*)Cv)[(size_t)row * N + col] = f2bf(vv);
                } else {
                    float* C = (float*)Cv;
                    C[(size_t)row * N + col] += vv + bias[col];
                }
            }
        }
    }
}

// ---------------------------------------------------------------------------
// Flash attention, S^T formulation. 512 thr = 8 waves, one (b,h), 128 q rows
// (16/wave, q = lane&15). Double-buffered K/V LDS -> ONE barrier per tile;
// in-register monotone mask; defer-max (T13), exp2 softmax, setprio (T5),
// length-based tile skip. (unchanged from r15 best)
// ---------------------------------------------------------------------------
__global__ __launch_bounds__(512) void attn_mfma(const ushort* __restrict__ QKV,
                                                 const ushort* __restrict__ Vt,
                                                 const int* __restrict__ mask,
                                                 ushort* __restrict__ O) {
    __shared__ __align__(16) ushort Kt[2][64 * 64];
    __shared__ __align__(16) ushort Vs[2][64 * 64];
    __shared__ __align__(16) ushort ps[8][16 * 72];  // per-wave P^T [q][key], stride 72
    __shared__ int lensh[8];

    const int tid = threadIdx.x, lane = tid & 63, w = tid >> 6;
    const int h = blockIdx.y, b = blockIdx.z;
    const int q0 = blockIdx.x * 128 + w * 16;
    const int fm = lane & 15, fq = lane >> 4;
    ushort* pw = &ps[w][0];
    const float L2E = 1.44269504f;

    // ---- sequence length for batch b (mask is monotone 1s then 0s) ----
    int part = mask[b * SEQ + tid] + mask[b * SEQ + 512 + tid];
#pragma unroll
    for (int off = 32; off > 0; off >>= 1) part += __shfl_xor(part, off, 64);
    if (lane == 0) lensh[w] = part;

    // Q as B-fragment, pre-scaled by 0.125 (exact in bf16: exponent shift)
    bf16x8 qf[2];
#pragma unroll
    for (int kk = 0; kk < 2; kk++) {
        bf16x8 t = *(const bf16x8*)&QKV[(size_t)(b * SEQ + q0 + fm) * QKVD + h * HDIM +
                                        kk * 32 + fq * 8];
#pragma unroll
        for (int j = 0; j < 8; j++) {
            union { float f; unsigned u; } vv;
            vv.u = ((unsigned)(ushort)t[j]) << 16;
            vv.f *= 0.125f;
            t[j] = (short)(ushort)(vv.u >> 16);   // exact: mantissa unchanged
        }
        qf[kk] = t;
    }

    // per-thread staging indices: 512 thr x 16B = one full 64x64 bf16 tile
    const int r0 = tid >> 3, c0 = tid & 7;
    const int dk0 = (r0 * 8 + (c0 ^ (r0 & 7))) * 16;

    auto gK = [&](int j0) {
        return (const uint4*)&QKV[(size_t)(b * SEQ + j0 + r0) * QKVD + 512 +
                                  h * HDIM + c0 * 8];
    };
    auto gV = [&](int j0) {
        return (const uint4*)&Vt[(size_t)((b * NH + h) * HDIM + r0) * SEQ + j0 + c0 * 8];
    };

    // ---- prologue: tile 0 into regs ----
    uint4 kreg = *gK(0);
    uint4 vreg = *gV(0);

    f32x4 oacc[4] = {};   // O^T: col = q (fm), rows dim = nt*16 + fq*4 + r
    float mrow = -INFINITY, lrow = 0.0f;
    int len = 0;
    int jmax = SEQ;       // provisional; fixed after first barrier

    for (int j0 = 0; j0 < jmax; j0 += 64) {
        const int buf = (j0 >> 6) & 1;
        // write tile j0 (in regs) to its LDS buffer, then the ONE barrier
        *(uint4*)((char*)Kt[buf] + dk0) = kreg;
        *(uint4*)((char*)Vs[buf] + dk0) = vreg;
        __syncthreads();
        if (j0 == 0) {    // lensh visible now (written pre-loop, pre-barrier)
            len = lensh[0] + lensh[1] + lensh[2] + lensh[3] +
                  lensh[4] + lensh[5] + lensh[6] + lensh[7];
            jmax = (len + 63) & ~63;   // >= 512 always (len >= SEQ/2)
        }
        const bool has_next = (j0 + 64 < jmax);
        if (has_next) {   // issue next-tile loads; latency hides under compute
            kreg = *gK(j0 + 64);
            vreg = *gV(j0 + 64);
        }

        // ---- S^T = K Q^T : lane holds q-col fm, keys nt*16 + fq*4 + r ----
        f32x4 sc[4] = {};
        __builtin_amdgcn_s_setprio(1);
#pragma unroll
        for (int nt = 0; nt < 4; nt++) {
            int key = nt * 16 + fm;
#pragma unroll
            for (int kk = 0; kk < 2; kk++) {
                bf16x8 kf = *(const bf16x8*)((char*)Kt[buf] +
                            (key * 8 + ((kk * 4 + fq) ^ (key & 7))) * 16);
                sc[nt] = __builtin_amdgcn_mfma_f32_16x16x32_bf16(kf, qf[kk], sc[nt], 0, 0, 0);
            }
        }
        __builtin_amdgcn_s_setprio(0);

        // ---- online softmax (defer-max, THR=8) over the lane's 16 keys ----
        float mx = -INFINITY;
#pragma unroll
        for (int nt = 0; nt < 4; nt++)
#pragma unroll
            for (int r = 0; r < 4; r++) mx = fmaxf(mx, sc[nt][r]);
        mx = fmaxf(mx, __shfl_xor(mx, 16));
        mx = fmaxf(mx, __shfl_xor(mx, 32));
        if (!__all(mx - mrow <= 8.0f)) {
            float mn = fmaxf(mrow, mx);
            float alpha = __expf(mrow - mn);
            mrow = mn;
            lrow *= alpha;
#pragma unroll
            for (int nt = 0; nt < 4; nt++)
#pragma unroll
                for (int r = 0; r < 4; r++) oacc[nt][r] *= alpha;
        }

        const float nm2 = -mrow * L2E;   // exp(s-m) == exp2(s*L2E - m*L2E)
        float sv[4][4];
        float ls = 0.0f;
        if (j0 + 64 <= len) {            // full tile: all keys valid (uniform)
#pragma unroll
            for (int nt = 0; nt < 4; nt++)
#pragma unroll
                for (int r = 0; r < 4; r++) {
                    float p = exp2f(fmaf(sc[nt][r], L2E, nm2));
                    sv[nt][r] = p;
                    ls += p;
                }
        } else {                          // tail tile: in-register mask
#pragma unroll
            for (int nt = 0; nt < 4; nt++)
#pragma unroll
                for (int r = 0; r < 4; r++) {
                    int key = j0 + nt * 16 + fq * 4 + r;
                    float p = (key < len) ? exp2f(fmaf(sc[nt][r], L2E, nm2)) : 0.0f;
                    sv[nt][r] = p;
                    ls += p;
                }
        }
        ls += __shfl_xor(ls, 16);
        ls += __shfl_xor(ls, 32);
        lrow += ls;

        // ---- P^T to per-wave LDS: pw[q=fm][key], trunc-to-bf16 packed ----
#pragma unroll
        for (int nt = 0; nt < 4; nt++) {
            union { float f; unsigned u; } a0, a1, a2, a3;
            a0.f = sv[nt][0]; a1.f = sv[nt][1]; a2.f = sv[nt][2]; a3.f = sv[nt][3];
            unsigned d0 = (a0.u >> 16) | (a1.u & 0xFFFF0000u);
            unsigned d1 = (a2.u >> 16) | (a3.u & 0xFFFF0000u);
            *(uint2*)&pw[fm * 72 + nt * 16 + fq * 4] = make_uint2(d0, d1);
        }

        // ---- O^T += V^T P^T ----
        __builtin_amdgcn_s_setprio(1);
#pragma unroll
        for (int kk = 0; kk < 2; kk++) {
            bf16x8 pf = *(const bf16x8*)&pw[fm * 72 + kk * 32 + fq * 8];
#pragma unroll
            for (int nt = 0; nt < 4; nt++) {
                int dim = nt * 16 + fm;
                bf16x8 vf = *(const bf16x8*)((char*)Vs[buf] +
                            (dim * 8 + ((kk * 4 + fq) ^ (dim & 7))) * 16);
                oacc[nt] = __builtin_amdgcn_mfma_f32_16x16x32_bf16(vf, pf, oacc[nt], 0, 0, 0);
            }
        }
        __builtin_amdgcn_s_setprio(0);
        // no trailing barrier: buf is next written at j0+128, after the
        // barrier at j0+64 which orders all reads of buf before that write
    }

    float inv = 1.0f / lrow;
#pragma unroll
    for (int nt = 0; nt < 4; nt++) {
        ushort4 o;
        o.x = f2bf(oacc[nt][0] * inv);
        o.y = f2bf(oacc[nt][1] * inv);
        o.z = f2bf(oacc[nt][2] * inv);
        o.w = f2bf(oacc[nt][3] * inv);
        *(ushort4*)&O[(size_t)(b * SEQ + q0 + fm) * DM + h * HDIM + nt * 16 + fq * 4] = o;
    }
}

// ---------------------------------------------------------------------------
extern "C" void kernel_launch(void* const* d_in, const int* in_sizes, int n_in,
                              void* d_out, int out_size, void* d_ws, size_t ws_size,
                              hipStream_t stream) {
    const float* x_in = (const float*)d_in[0];
    const int* mask   = (const int*)d_in[1];
    const float* Wq   = (const float*)d_in[2];
    const float* Wk   = (const float*)d_in[3];
    const float* Wv   = (const float*)d_in[4];
    const float* Wo   = (const float*)d_in[5];
    const float* ln1g = (const float*)d_in[6];
    const float* ln1b = (const float*)d_in[7];
    const float* ln2g = (const float*)d_in[8];
    const float* ln2b = (const float*)d_in[9];
    const float* W1   = (const float*)d_in[10];
    const float* b1   = (const float*)d_in[11];
    const float* W2   = (const float*)d_in[12];
    const float* b2   = (const float*)d_in[13];

    float* x = (float*)d_out;  // fp32 residual stream
    ushort* wsb = (ushort*)d_ws;
    const size_t U = 1048576;
    ushort* WqkvT = wsb;            // [L][1536][512]  (3U)
    ushort* WoT   = wsb + 3 * U;    // [L][512][512]   (1U)
    ushort* W1T   = wsb + 4 * U;    // [L][2048][512]  (4U)
    ushort* W2T   = wsb + 8 * U;    // [L][512][2048]  (4U)
    ushort* hb    = wsb + 12 * U;   // bf16 [8192][512]
    ushort* qkv   = wsb + 16 * U;   // bf16 [8192][1536] (12U; V region dead)
    ushort* ob    = wsb + 28 * U;   // bf16 [8192][512]
    ushort* vTb   = wsb + 32 * U;   // bf16 [8][512][1024]
    ushort* f1b   = qkv;            // 16U alias (qkv+ob), dead during FFN

    // Merged weight convert+transpose (graph-safe: every launch)
    wtrans_all<<<dim3(3072, 1, 4), 256, 0, stream>>>(Wq, Wk, Wv, Wo, W1, W2,
                                                     WqkvT, WoT, W1T, W2T);

    add_pos_kernel<<<(NTOK * DM / 4) / 256, 256, 0, stream>>>(x_in, x);

    dim3 gQKV(QKVD / 128, NTOK / 128);   // (12, 64)  = 768 blocks, 3/CU
    dim3 gProj(DM / 64, NTOK / 64);      // (8, 128)  = 1024 blocks
    dim3 gFF1(DFF / 128, NTOK / 128);    // (16, 64)  = 1024 blocks, 4/CU
    dim3 gFF2(DM / 64, NTOK / 64);       // (8, 128)  = 1024 blocks
    dim3 gAttn(SEQ / 128, NH, NB);       // (8, 8, 8) = 512 blocks x 8 waves

    for (int l = 0; l < NLAYER; l++) {
        const size_t wOff   = (size_t)l * 262144;
        const size_t wqkvOff= (size_t)l * 786432;
        const size_t w1Off  = (size_t)l * 1048576;

        ln_kernel<<<NTOK / 4, 256, 0, stream>>>(x, ln1g + l * DM, ln1b + l * DM, hb);
        gemm_bf16<128, 128, 1, 5><<<gQKV, 512, 0, stream>>>(hb, WqkvT + wqkvOff, nullptr,
                                                            qkv, vTb, NTOK, QKVD, DM);
        attn_mfma<<<gAttn, 512, 0, stream>>>(qkv, vTb, mask, ob);
        gemm_bf16<64, 64, 2, 1, 3><<<gProj, 512, 0, stream>>>(ob, WoT + wOff, nullptr, x,
                                                              nullptr, NTOK, DM, DM);
        ln_kernel<<<NTOK / 4, 256, 0, stream>>>(x, ln2g + l * DM, ln2b + l * DM, hb);
        gemm_bf16<128, 128, 1, 2><<<gFF1, 512, 0, stream>>>(hb, W1T + w1Off,
                                                            b1 + (size_t)l * DFF, f1b,
                                                            nullptr, NTOK, DFF, DM);
        gemm_bf16<64, 64, 2, 3, 3><<<gFF2, 512, 0, stream>>>(f1b, W2T + w1Off,
                                                             b2 + (size_t)l * DM, x,
                                                             nullptr, NTOK, DM, DFF);
    }
}

// Round 17
// 686.264 us; speedup vs baseline: 1.1272x; 1.1272x over previous
//
#include <hip/hip_runtime.h>
#include <math.h>

// Problem constants
#define NB 8
#define SEQ 1024
#define DM 512
#define NH 8
#define HDIM 64
#define DFF 2048
#define NLAYER 4
#define NTOK (NB * SEQ)   // 8192
#define QKVD 1536         // fused q|k|v row width

typedef __attribute__((ext_vector_type(8))) short bf16x8;
typedef __attribute__((ext_vector_type(4))) float f32x4;

__device__ __forceinline__ ushort f2bf(float f) {
    union { float f; unsigned u; } v; v.f = f;
    unsigned r = (v.u + 0x7FFF + ((v.u >> 16) & 1)) >> 16;  // RNE
    return (ushort)r;
}

// async global->LDS, 16B per lane
__device__ __forceinline__ void async16(const void* g, void* l) {
    __builtin_amdgcn_global_load_lds(
        (const __attribute__((address_space(1))) unsigned int*)g,
        (__attribute__((address_space(3))) unsigned int*)l, 16, 0, 0);
}

// ---------------------------------------------------------------------------
// Positional encoding add
// ---------------------------------------------------------------------------
__global__ __launch_bounds__(256) void add_pos_kernel(const float* __restrict__ x,
                                                      float* __restrict__ out) {
    int idx4 = blockIdx.x * blockDim.x + threadIdx.x;
    int base = idx4 * 4;
    int d = base & (DM - 1);
    int s = (base >> 9) & (SEQ - 1);
    float4 v = *(const float4*)&x[base];
    float r[4] = {v.x, v.y, v.z, v.w};
#pragma unroll
    for (int i = 0; i < 4; i++) {
        int dd = d + i;
        float pe;
        if (dd < 256) {
            float inv = powf(10000.0f, 2.0f * (float)dd / 512.0f);
            pe = sinf((float)s / inv);
        } else {
            float inv = powf(10000.0f, 2.0f * (float)(dd - 256) / 512.0f);
            pe = cosf((float)s / inv);
        }
        r[i] += pe;
    }
    *(float4*)&out[base] = make_float4(r[0], r[1], r[2], r[3]);
}

// ---------------------------------------------------------------------------
// Merged weight convert+transpose: ALL 6 weight tensors in ONE dispatch.
// Flat grid x = 3072 blocks/layer (segment table below), z = layer.
// ---------------------------------------------------------------------------
__global__ __launch_bounds__(256) void wtrans_all(
    const float* __restrict__ Wq, const float* __restrict__ Wk,
    const float* __restrict__ Wv, const float* __restrict__ Wo,
    const float* __restrict__ W1, const float* __restrict__ W2,
    ushort* __restrict__ WqkvT, ushort* __restrict__ WoT,
    ushort* __restrict__ W1T, ushort* __restrict__ W2T) {
    __shared__ float tile[32][36];
    const int l = blockIdx.z;
    const int bid = blockIdx.x;
    const float* src; ushort* dst;
    int K, N, rowOff, stride, t, nxk;
    if (bid < 1024) {
        int seg = bid >> 8; t = bid & 255;
        K = 512; N = 512; nxk = 16;
        if (seg == 0)      { src = Wq; dst = WqkvT; rowOff = 0;    stride = 786432; }
        else if (seg == 1) { src = Wk; dst = WqkvT; rowOff = 512;  stride = 786432; }
        else if (seg == 2) { src = Wv; dst = WqkvT; rowOff = 1024; stride = 786432; }
        else               { src = Wo; dst = WoT;   rowOff = 0;    stride = 262144; }
    } else if (bid < 2048) {
        t = bid - 1024; K = 512; N = 2048; nxk = 64;
        src = W1; dst = W1T; rowOff = 0; stride = 1048576;
    } else {
        t = bid - 2048; K = 2048; N = 512; nxk = 16;
        src = W2; dst = W2T; rowOff = 0; stride = 1048576;
    }
    const int bx = t % nxk, by = t / nxk;
    const int kb = by * 32, nb = bx * 32;
    const float* s = src + (size_t)l * K * N;
    ushort* d = dst + (size_t)l * stride;
    int r = threadIdx.x >> 3, c4 = (threadIdx.x & 7) * 4;
    float4 v = *(const float4*)&s[(size_t)(kb + r) * N + nb + c4];
    *(float4*)&tile[r][c4] = v;
    __syncthreads();
    ushort4 o;
    o.x = f2bf(tile[c4 + 0][r]);
    o.y = f2bf(tile[c4 + 1][r]);
    o.z = f2bf(tile[c4 + 2][r]);
    o.w = f2bf(tile[c4 + 3][r]);
    *(ushort4*)&d[(size_t)(rowOff + nb + r) * K + kb + c4] = o;
}

// ---------------------------------------------------------------------------
// LayerNorm fp32 in -> bf16 out. One wave per row, 4 rows/block.
// ---------------------------------------------------------------------------
__global__ __launch_bounds__(256) void ln_kernel(const float* __restrict__ x,
                                                 const float* __restrict__ g,
                                                 const float* __restrict__ bta,
                                                 ushort* __restrict__ out) {
    int w = threadIdx.x >> 6;
    int lane = threadIdx.x & 63;
    size_t row = (size_t)blockIdx.x * 4 + w;
    const float* xr = x + row * DM;
    float4 v0 = *(const float4*)&xr[lane * 4];
    float4 v1 = *(const float4*)&xr[256 + lane * 4];
    float sum = v0.x + v0.y + v0.z + v0.w + v1.x + v1.y + v1.z + v1.w;
#pragma unroll
    for (int off = 32; off > 0; off >>= 1) sum += __shfl_xor(sum, off, 64);
    float mu = sum * (1.0f / 512.0f);
    float d0[8] = {v0.x - mu, v0.y - mu, v0.z - mu, v0.w - mu,
                   v1.x - mu, v1.y - mu, v1.z - mu, v1.w - mu};
    float sq = 0.0f;
#pragma unroll
    for (int i = 0; i < 8; i++) sq = fmaf(d0[i], d0[i], sq);
#pragma unroll
    for (int off = 32; off > 0; off >>= 1) sq += __shfl_xor(sq, off, 64);
    float rs = rsqrtf(sq * (1.0f / 512.0f) + 1e-3f);
    float4 g0 = *(const float4*)&g[lane * 4];
    float4 g1 = *(const float4*)&g[256 + lane * 4];
    float4 b0 = *(const float4*)&bta[lane * 4];
    float4 b1 = *(const float4*)&bta[256 + lane * 4];
    ushort* orow = out + row * DM;
    ushort4 o0, o1;
    o0.x = f2bf(fmaf(d0[0] * rs, g0.x, b0.x));
    o0.y = f2bf(fmaf(d0[1] * rs, g0.y, b0.y));
    o0.z = f2bf(fmaf(d0[2] * rs, g0.z, b0.z));
    o0.w = f2bf(fmaf(d0[3] * rs, g0.w, b0.w));
    o1.x = f2bf(fmaf(d0[4] * rs, g1.x, b1.x));
    o1.y = f2bf(fmaf(d0[5] * rs, g1.y, b1.y));
    o1.z = f2bf(fmaf(d0[6] * rs, g1.z, b1.z));
    o1.w = f2bf(fmaf(d0[7] * rs, g1.w, b1.w));
    *(ushort4*)&orow[lane * 4] = o0;
    *(ushort4*)&orow[256 + lane * 4] = o1;
}

// ---------------------------------------------------------------------------
// bf16 MFMA GEMM, BM x BN tile, BK = 32*KH, 8 waves (4x2), 512 threads,
// double-buffered LDS (r5 2-phase sync structure), T1 bijective XCD swizzle
// (requires gridDim.y % 8 == 0).
// Tile sizes sit at the measured optimum of 3-4 blocks/CU (r12/r14 config;
// 2/CU (r13), 6/CU (r5), counted-vmcnt ring (r6/r16), split-K (r7) all
// measured worse — this 2-phase drain-to-zero structure at 3-4 blocks/CU
// is the converged optimum of this template family on these shapes).
// Per wave: (BM/4) x (BN/2) output = FM x FN 16x16 frags, FM=BM/64, FN=BN/32.
// MODE: 0 = bf16 store; 1 = fp32 +=; 2 = bias+relu -> bf16; 3 = bias + fp32 +=
//       5 = QKV fused: Q/K col-blocks -> bf16 store; V col-blocks (n0>=1024)
//           -> TRANSPOSED ushort4 store to aux = vT[b][c][s]
// ---------------------------------------------------------------------------
template <int BM, int BN, int KH, int MODE>
__global__ __launch_bounds__(512) void gemm_bf16(const ushort* __restrict__ A,
                                                 const ushort* __restrict__ Bt,
                                                 const float* __restrict__ bias,
                                                 void* __restrict__ Cv,
                                                 void* __restrict__ aux,
                                                 int M, int N, int K) {
    static_assert(BM % 64 == 0 && BN % 64 == 0, "tile multiple of 64");
    constexpr int FM = BM / 64;   // frags per wave, rows (wave grid 4x2)
    constexpr int FN = BN / 32;   // frags per wave, cols
    __shared__ __align__(16) ushort As[2][KH * BM * 32];
    __shared__ __align__(16) ushort Bs[2][KH * BN * 32];
    const int tid = threadIdx.x;
    const int lane = tid & 63;
    const int w = tid >> 6;                  // 0..7

    // --- XCD-locality swizzle (bijective for gridDim.y % 8 == 0) ---
    const int nx = gridDim.x;
    int wg = blockIdx.y * nx + blockIdx.x;   // hw linear dispatch id
    int xcd = wg & 7;
    int t0 = wg >> 3;
    int bx = t0 % nx;
    int by = (t0 / nx) * 8 + xcd;            // same-by blocks share xcd
    const int m0 = by * BM, n0 = bx * BN;

    const int wm = (w >> 1) * (BM / 4);      // wave row (0..3)
    const int wn = (w & 1) * (BN / 2);       // wave col (0..1)
    const int fm = lane & 15, fq = lane >> 4;

    f32x4 acc[FM][FN] = {};

    // stage K-tile [kt, kt+32*KH) into LDS buffer buf (async, wave-linear).
    // chunks16 per hf: A = BM*4, B = BN*4 (each 32-elem row = 4 x 16B).
    auto stage = [&](int buf, int kt) {
#pragma unroll
        for (int hf = 0; hf < KH; hf++) {
            constexpr int CA = BM * 4;
            if constexpr (CA >= 512) {
#pragma unroll
                for (int u = 0; u < CA / 512; u++) {
                    int chunk = u * 512 + tid;
                    int row = chunk >> 2, c = chunk & 3;
                    async16(&A[(size_t)(m0 + row) * K + kt + hf * 32 + c * 8],
                            (char*)As[buf] + hf * BM * 64 + chunk * 16);
                }
            } else {
                if (tid < CA) {
                    int chunk = tid;
                    int row = chunk >> 2, c = chunk & 3;
                    async16(&A[(size_t)(m0 + row) * K + kt + hf * 32 + c * 8],
                            (char*)As[buf] + hf * BM * 64 + chunk * 16);
                }
            }
            constexpr int CB = BN * 4;
            if constexpr (CB >= 512) {
#pragma unroll
                for (int u = 0; u < CB / 512; u++) {
                    int chunk = u * 512 + tid;
                    int row = chunk >> 2, c = chunk & 3;
                    async16(&Bt[(size_t)(n0 + row) * K + kt + hf * 32 + c * 8],
                            (char*)Bs[buf] + hf * BN * 64 + chunk * 16);
                }
            } else {
                if (tid < CB) {
                    int chunk = tid;
                    int row = chunk >> 2, c = chunk & 3;
                    async16(&Bt[(size_t)(n0 + row) * K + kt + hf * 32 + c * 8],
                            (char*)Bs[buf] + hf * BN * 64 + chunk * 16);
                }
            }
        }
    };

    stage(0, 0);
    __syncthreads();
    int cur = 0;
    for (int kt = 0; kt < K; kt += 32 * KH) {
        if (kt + 32 * KH < K) stage(cur ^ 1, kt + 32 * KH);  // prefetch next
#pragma unroll
        for (int hf = 0; hf < KH; hf++) {
            bf16x8 af[FM], bfr[FN];
#pragma unroll
            for (int i = 0; i < FM; i++)
                af[i] = *(const bf16x8*)&As[cur][hf * BM * 32 +
                                                 (wm + i * 16 + fm) * 32 + fq * 8];
#pragma unroll
            for (int j = 0; j < FN; j++)
                bfr[j] = *(const bf16x8*)&Bs[cur][hf * BN * 32 +
                                                  (wn + j * 16 + fm) * 32 + fq * 8];
#pragma unroll
            for (int i = 0; i < FM; i++)
#pragma unroll
                for (int j = 0; j < FN; j++)
                    acc[i][j] = __builtin_amdgcn_mfma_f32_16x16x32_bf16(
                        af[i], bfr[j], acc[i][j], 0, 0, 0);
        }
        __syncthreads();   // drains prefetch (vmcnt) + ds_reads (lgkmcnt)
        cur ^= 1;
    }

    if constexpr (MODE == 5) {
        if (n0 >= 1024) {
            // V col-block: transposed write to vT[b][c][s]; acc rows are 4
            // consecutive s at fixed c -> one 8B ushort4 store per frag.
            ushort* vT = (ushort*)aux;
            const int b = m0 >> 10;               // BM tiles never cross batch
            const int sl = (m0 & (SEQ - 1)) + wm + fq * 4;
#pragma unroll
            for (int i = 0; i < FM; i++) {
#pragma unroll
                for (int j = 0; j < FN; j++) {
                    int c = n0 - 1024 + wn + j * 16 + fm;
                    ushort4 o;
                    o.x = f2bf(acc[i][j][0]);
                    o.y = f2bf(acc[i][j][1]);
                    o.z = f2bf(acc[i][j][2]);
                    o.w = f2bf(acc[i][j][3]);
                    *(ushort4*)&vT[(size_t)(b * DM + c) * SEQ + sl + i * 16] = o;
                }
            }
        } else {
            // Q/K col-block: normal bf16 store
#pragma unroll
            for (int i = 0; i < FM; i++)
#pragma unroll
                for (int j = 0; j < FN; j++) {
                    int col = n0 + wn + j * 16 + fm;
#pragma unroll
                    for (int r = 0; r < 4; r++) {
                        int row = m0 + wm + i * 16 + fq * 4 + r;
                        ((ushort*)Cv)[(size_t)row * N + col] = f2bf(acc[i][j][r]);
                    }
                }
        }
        return;
    }

#pragma unroll
    for (int i = 0; i < FM; i++) {
#pragma unroll
        for (int j = 0; j < FN; j++) {
            int col = n0 + wn + j * 16 + fm;
#pragma unroll
            for (int r = 0; r < 4; r++) {
                int row = m0 + wm + i * 16 + fq * 4 + r;
                float vv = acc[i][j][r];
                if constexpr (MODE == 0) {
                    ((ushort*)Cv)[(size_t)row * N + col] = f2bf(vv);
                } else if constexpr (MODE == 1) {
                    float* C = (float*)Cv;
                    C[(size_t)row * N + col] += vv;
                } else if constexpr (MODE == 2) {
                    vv += bias[col];
                    vv = fmaxf(vv, 0.0f);
                    ((ushort*)Cv)[(size_t)row * N + col] = f2bf(vv);
                } else {
                    float* C = (float*)Cv;
                    C[(size_t)row * N + col] += vv + bias[col];
                }
            }
        }
    }
}

// ---------------------------------------------------------------------------
// Flash attention, S^T formulation. 512 thr = 8 waves, one (b,h), 128 q rows
// (16/wave, q = lane&15). Double-buffered K/V LDS -> ONE barrier per tile
// (write buf[t] -> barrier -> prefetch t+1 -> compute buf[t]; buf is
// rewritten at t+2, after barrier(t+1), which all waves cross only after
// finishing their reads at t). In-register monotone mask; full tiles skip
// the compare (wave-uniform). Defer-max (T13), exp2 softmax, setprio (T5),
// length-based tile skip.
// ---------------------------------------------------------------------------
__global__ __launch_bounds__(512) void attn_mfma(const ushort* __restrict__ QKV,
                                                 const ushort* __restrict__ Vt,
                                                 const int* __restrict__ mask,
                                                 ushort* __restrict__ O) {
    __shared__ __align__(16) ushort Kt[2][64 * 64];
    __shared__ __align__(16) ushort Vs[2][64 * 64];
    __shared__ __align__(16) ushort ps[8][16 * 72];  // per-wave P^T [q][key], stride 72
    __shared__ int lensh[8];

    const int tid = threadIdx.x, lane = tid & 63, w = tid >> 6;
    const int h = blockIdx.y, b = blockIdx.z;
    const int q0 = blockIdx.x * 128 + w * 16;
    const int fm = lane & 15, fq = lane >> 4;
    ushort* pw = &ps[w][0];
    const float L2E = 1.44269504f;

    // ---- sequence length for batch b (mask is monotone 1s then 0s) ----
    int part = mask[b * SEQ + tid] + mask[b * SEQ + 512 + tid];
#pragma unroll
    for (int off = 32; off > 0; off >>= 1) part += __shfl_xor(part, off, 64);
    if (lane == 0) lensh[w] = part;

    // Q as B-fragment, pre-scaled by 0.125 (exact in bf16: exponent shift)
    bf16x8 qf[2];
#pragma unroll
    for (int kk = 0; kk < 2; kk++) {
        bf16x8 t = *(const bf16x8*)&QKV[(size_t)(b * SEQ + q0 + fm) * QKVD + h * HDIM +
                                        kk * 32 + fq * 8];
#pragma unroll
        for (int j = 0; j < 8; j++) {
            union { float f; unsigned u; } vv;
            vv.u = ((unsigned)(ushort)t[j]) << 16;
            vv.f *= 0.125f;
            t[j] = (short)(ushort)(vv.u >> 16);   // exact: mantissa unchanged
        }
        qf[kk] = t;
    }

    // per-thread staging indices: 512 thr x 16B = one full 64x64 bf16 tile
    const int r0 = tid >> 3, c0 = tid & 7;
    const int dk0 = (r0 * 8 + (c0 ^ (r0 & 7))) * 16;

    auto gK = [&](int j0) {
        return (const uint4*)&QKV[(size_t)(b * SEQ + j0 + r0) * QKVD + 512 +
                                  h * HDIM + c0 * 8];
    };
    auto gV = [&](int j0) {
        return (const uint4*)&Vt[(size_t)((b * NH + h) * HDIM + r0) * SEQ + j0 + c0 * 8];
    };

    // ---- prologue: tile 0 into regs ----
    uint4 kreg = *gK(0);
    uint4 vreg = *gV(0);

    f32x4 oacc[4] = {};   // O^T: col = q (fm), rows dim = nt*16 + fq*4 + r
    float mrow = -INFINITY, lrow = 0.0f;
    int len = 0;
    int jmax = SEQ;       // provisional; fixed after first barrier

    for (int j0 = 0; j0 < jmax; j0 += 64) {
        const int buf = (j0 >> 6) & 1;
        // write tile j0 (in regs) to its LDS buffer, then the ONE barrier
        *(uint4*)((char*)Kt[buf] + dk0) = kreg;
        *(uint4*)((char*)Vs[buf] + dk0) = vreg;
        __syncthreads();
        if (j0 == 0) {    // lensh visible now (written pre-loop, pre-barrier)
            len = lensh[0] + lensh[1] + lensh[2] + lensh[3] +
                  lensh[4] + lensh[5] + lensh[6] + lensh[7];
            jmax = (len + 63) & ~63;   // >= 512 always (len >= SEQ/2)
        }
        const bool has_next = (j0 + 64 < jmax);
        if (has_next) {   // issue next-tile loads; latency hides under compute
            kreg = *gK(j0 + 64);
            vreg = *gV(j0 + 64);
        }

        // ---- S^T = K Q^T : lane holds q-col fm, keys nt*16 + fq*4 + r ----
        f32x4 sc[4] = {};
        __builtin_amdgcn_s_setprio(1);
#pragma unroll
        for (int nt = 0; nt < 4; nt++) {
            int key = nt * 16 + fm;
#pragma unroll
            for (int kk = 0; kk < 2; kk++) {
                bf16x8 kf = *(const bf16x8*)((char*)Kt[buf] +
                            (key * 8 + ((kk * 4 + fq) ^ (key & 7))) * 16);
                sc[nt] = __builtin_amdgcn_mfma_f32_16x16x32_bf16(kf, qf[kk], sc[nt], 0, 0, 0);
            }
        }
        __builtin_amdgcn_s_setprio(0);

        // ---- online softmax (defer-max, THR=8) over the lane's 16 keys ----
        float mx = -INFINITY;
#pragma unroll
        for (int nt = 0; nt < 4; nt++)
#pragma unroll
            for (int r = 0; r < 4; r++) mx = fmaxf(mx, sc[nt][r]);
        mx = fmaxf(mx, __shfl_xor(mx, 16));
        mx = fmaxf(mx, __shfl_xor(mx, 32));
        if (!__all(mx - mrow <= 8.0f)) {
            float mn = fmaxf(mrow, mx);
            float alpha = __expf(mrow - mn);
            mrow = mn;
            lrow *= alpha;
#pragma unroll
            for (int nt = 0; nt < 4; nt++)
#pragma unroll
                for (int r = 0; r < 4; r++) oacc[nt][r] *= alpha;
        }

        const float nm2 = -mrow * L2E;   // exp(s-m) == exp2(s*L2E - m*L2E)
        float sv[4][4];
        float ls = 0.0f;
        if (j0 + 64 <= len) {            // full tile: all keys valid (uniform)
#pragma unroll
            for (int nt = 0; nt < 4; nt++)
#pragma unroll
                for (int r = 0; r < 4; r++) {
                    float p = exp2f(fmaf(sc[nt][r], L2E, nm2));
                    sv[nt][r] = p;
                    ls += p;
                }
        } else {                          // tail tile: in-register mask
#pragma unroll
            for (int nt = 0; nt < 4; nt++)
#pragma unroll
                for (int r = 0; r < 4; r++) {
                    int key = j0 + nt * 16 + fq * 4 + r;
                    float p = (key < len) ? exp2f(fmaf(sc[nt][r], L2E, nm2)) : 0.0f;
                    sv[nt][r] = p;
                    ls += p;
                }
        }
        ls += __shfl_xor(ls, 16);
        ls += __shfl_xor(ls, 32);
        lrow += ls;

        // ---- P^T to per-wave LDS: pw[q=fm][key], trunc-to-bf16 packed ----
#pragma unroll
        for (int nt = 0; nt < 4; nt++) {
            union { float f; unsigned u; } a0, a1, a2, a3;
            a0.f = sv[nt][0]; a1.f = sv[nt][1]; a2.f = sv[nt][2]; a3.f = sv[nt][3];
            unsigned d0 = (a0.u >> 16) | (a1.u & 0xFFFF0000u);
            unsigned d1 = (a2.u >> 16) | (a3.u & 0xFFFF0000u);
            *(uint2*)&pw[fm * 72 + nt * 16 + fq * 4] = make_uint2(d0, d1);
        }

        // ---- O^T += V^T P^T ----
        __builtin_amdgcn_s_setprio(1);
#pragma unroll
        for (int kk = 0; kk < 2; kk++) {
            bf16x8 pf = *(const bf16x8*)&pw[fm * 72 + kk * 32 + fq * 8];
#pragma unroll
            for (int nt = 0; nt < 4; nt++) {
                int dim = nt * 16 + fm;
                bf16x8 vf = *(const bf16x8*)((char*)Vs[buf] +
                            (dim * 8 + ((kk * 4 + fq) ^ (dim & 7))) * 16);
                oacc[nt] = __builtin_amdgcn_mfma_f32_16x16x32_bf16(vf, pf, oacc[nt], 0, 0, 0);
            }
        }
        __builtin_amdgcn_s_setprio(0);
        // no trailing barrier: buf is next written at j0+128, after the
        // barrier at j0+64 which orders all reads of buf before that write
    }

    float inv = 1.0f / lrow;
#pragma unroll
    for (int nt = 0; nt < 4; nt++) {
        ushort4 o;
        o.x = f2bf(oacc[nt][0] * inv);
        o.y = f2bf(oacc[nt][1] * inv);
        o.z = f2bf(oacc[nt][2] * inv);
        o.w = f2bf(oacc[nt][3] * inv);
        *(ushort4*)&O[(size_t)(b * SEQ + q0 + fm) * DM + h * HDIM + nt * 16 + fq * 4] = o;
    }
}

// ---------------------------------------------------------------------------
extern "C" void kernel_launch(void* const* d_in, const int* in_sizes, int n_in,
                              void* d_out, int out_size, void* d_ws, size_t ws_size,
                              hipStream_t stream) {
    const float* x_in = (const float*)d_in[0];
    const int* mask   = (const int*)d_in[1];
    const float* Wq   = (const float*)d_in[2];
    const float* Wk   = (const float*)d_in[3];
    const float* Wv   = (const float*)d_in[4];
    const float* Wo   = (const float*)d_in[5];
    const float* ln1g = (const float*)d_in[6];
    const float* ln1b = (const float*)d_in[7];
    const float* ln2g = (const float*)d_in[8];
    const float* ln2b = (const float*)d_in[9];
    const float* W1   = (const float*)d_in[10];
    const float* b1   = (const float*)d_in[11];
    const float* W2   = (const float*)d_in[12];
    const float* b2   = (const float*)d_in[13];

    float* x = (float*)d_out;  // fp32 residual stream
    ushort* wsb = (ushort*)d_ws;
    const size_t U = 1048576;
    ushort* WqkvT = wsb;            // [L][1536][512]  (3U)
    ushort* WoT   = wsb + 3 * U;    // [L][512][512]   (1U)
    ushort* W1T   = wsb + 4 * U;    // [L][2048][512]  (4U)
    ushort* W2T   = wsb + 8 * U;    // [L][512][2048]  (4U)
    ushort* hb    = wsb + 12 * U;   // bf16 [8192][512]
    ushort* qkv   = wsb + 16 * U;   // bf16 [8192][1536] (12U; V region dead)
    ushort* ob    = wsb + 28 * U;   // bf16 [8192][512]
    ushort* vTb   = wsb + 32 * U;   // bf16 [8][512][1024]
    ushort* f1b   = qkv;            // 16U alias (qkv+ob), dead during FFN

    // Merged weight convert+transpose (graph-safe: every launch)
    wtrans_all<<<dim3(3072, 1, 4), 256, 0, stream>>>(Wq, Wk, Wv, Wo, W1, W2,
                                                     WqkvT, WoT, W1T, W2T);

    add_pos_kernel<<<(NTOK * DM / 4) / 256, 256, 0, stream>>>(x_in, x);

    dim3 gQKV(QKVD / 128, NTOK / 128);   // (12, 64)  = 768 blocks, 3/CU
    dim3 gProj(DM / 64, NTOK / 64);      // (8, 128)  = 1024 blocks, 4/CU
    dim3 gFF1(DFF / 128, NTOK / 128);    // (16, 64)  = 1024 blocks, 4/CU
    dim3 gFF2(DM / 64, NTOK / 64);       // (8, 128)  = 1024 blocks, 4/CU
    dim3 gAttn(SEQ / 128, NH, NB);       // (8, 8, 8) = 512 blocks x 8 waves

    for (int l = 0; l < NLAYER; l++) {
        const size_t wOff   = (size_t)l * 262144;
        const size_t wqkvOff= (size_t)l * 786432;
        const size_t w1Off  = (size_t)l * 1048576;

        ln_kernel<<<NTOK / 4, 256, 0, stream>>>(x, ln1g + l * DM, ln1b + l * DM, hb);
        gemm_bf16<128, 128, 1, 5><<<gQKV, 512, 0, stream>>>(hb, WqkvT + wqkvOff, nullptr,
                                                            qkv, vTb, NTOK, QKVD, DM);
        attn_mfma<<<gAttn, 512, 0, stream>>>(qkv, vTb, mask, ob);
        gemm_bf16<64, 64, 2, 1><<<gProj, 512, 0, stream>>>(ob, WoT + wOff, nullptr, x,
                                                           nullptr, NTOK, DM, DM);
        ln_kernel<<<NTOK / 4, 256, 0, stream>>>(x, ln2g + l * DM, ln2b + l * DM, hb);
        gemm_bf16<128, 128, 1, 2><<<gFF1, 512, 0, stream>>>(hb, W1T + w1Off,
                                                            b1 + (size_t)l * DFF, f1b,
                                                            nullptr, NTOK, DFF, DM);
        gemm_bf16<64, 64, 2, 3><<<gFF2, 512, 0, stream>>>(f1b, W2T + w1Off,
                                                          b2 + (size_t)l * DM, x,
                                                          nullptr, NTOK, DM, DFF);
    }
}

// Round 18
// 685.856 us; speedup vs baseline: 1.1279x; 1.0006x over previous
//
#include <hip/hip_runtime.h>
#include <math.h>

// Problem constants
#define NB 8
#define SEQ 1024
#define DM 512
#define NH 8
#define HDIM 64
#define DFF 2048
#define NLAYER 4
#define NTOK (NB * SEQ)   // 8192
#define QKVD 1536         // fused q|k|v row width

typedef __attribute__((ext_vector_type(8))) short bf16x8;
typedef __attribute__((ext_vector_type(4))) float f32x4;

__device__ __forceinline__ ushort f2bf(float f) {
    union { float f; unsigned u; } v; v.f = f;
    unsigned r = (v.u + 0x7FFF + ((v.u >> 16) & 1)) >> 16;  // RNE
    return (ushort)r;
}

// async global->LDS, 16B per lane
__device__ __forceinline__ void async16(const void* g, void* l) {
    __builtin_amdgcn_global_load_lds(
        (const __attribute__((address_space(1))) unsigned int*)g,
        (__attribute__((address_space(3))) unsigned int*)l, 16, 0, 0);
}

// ---------------------------------------------------------------------------
// Positional encoding add
// ---------------------------------------------------------------------------
__global__ __launch_bounds__(256) void add_pos_kernel(const float* __restrict__ x,
                                                      float* __restrict__ out) {
    int idx4 = blockIdx.x * blockDim.x + threadIdx.x;
    int base = idx4 * 4;
    int d = base & (DM - 1);
    int s = (base >> 9) & (SEQ - 1);
    float4 v = *(const float4*)&x[base];
    float r[4] = {v.x, v.y, v.z, v.w};
#pragma unroll
    for (int i = 0; i < 4; i++) {
        int dd = d + i;
        float pe;
        if (dd < 256) {
            float inv = powf(10000.0f, 2.0f * (float)dd / 512.0f);
            pe = sinf((float)s / inv);
        } else {
            float inv = powf(10000.0f, 2.0f * (float)(dd - 256) / 512.0f);
            pe = cosf((float)s / inv);
        }
        r[i] += pe;
    }
    *(float4*)&out[base] = make_float4(r[0], r[1], r[2], r[3]);
}

// ---------------------------------------------------------------------------
// Merged weight convert+transpose: ALL 6 weight tensors in ONE dispatch.
// Flat grid x = 3072 blocks/layer (segment table below), z = layer.
// ---------------------------------------------------------------------------
__global__ __launch_bounds__(256) void wtrans_all(
    const float* __restrict__ Wq, const float* __restrict__ Wk,
    const float* __restrict__ Wv, const float* __restrict__ Wo,
    const float* __restrict__ W1, const float* __restrict__ W2,
    ushort* __restrict__ WqkvT, ushort* __restrict__ WoT,
    ushort* __restrict__ W1T, ushort* __restrict__ W2T) {
    __shared__ float tile[32][36];
    const int l = blockIdx.z;
    const int bid = blockIdx.x;
    const float* src; ushort* dst;
    int K, N, rowOff, stride, t, nxk;
    if (bid < 1024) {
        int seg = bid >> 8; t = bid & 255;
        K = 512; N = 512; nxk = 16;
        if (seg == 0)      { src = Wq; dst = WqkvT; rowOff = 0;    stride = 786432; }
        else if (seg == 1) { src = Wk; dst = WqkvT; rowOff = 512;  stride = 786432; }
        else if (seg == 2) { src = Wv; dst = WqkvT; rowOff = 1024; stride = 786432; }
        else               { src = Wo; dst = WoT;   rowOff = 0;    stride = 262144; }
    } else if (bid < 2048) {
        t = bid - 1024; K = 512; N = 2048; nxk = 64;
        src = W1; dst = W1T; rowOff = 0; stride = 1048576;
    } else {
        t = bid - 2048; K = 2048; N = 512; nxk = 16;
        src = W2; dst = W2T; rowOff = 0; stride = 1048576;
    }
    const int bx = t % nxk, by = t / nxk;
    const int kb = by * 32, nb = bx * 32;
    const float* s = src + (size_t)l * K * N;
    ushort* d = dst + (size_t)l * stride;
    int r = threadIdx.x >> 3, c4 = (threadIdx.x & 7) * 4;
    float4 v = *(const float4*)&s[(size_t)(kb + r) * N + nb + c4];
    *(float4*)&tile[r][c4] = v;
    __syncthreads();
    ushort4 o;
    o.x = f2bf(tile[c4 + 0][r]);
    o.y = f2bf(tile[c4 + 1][r]);
    o.z = f2bf(tile[c4 + 2][r]);
    o.w = f2bf(tile[c4 + 3][r]);
    *(ushort4*)&d[(size_t)(rowOff + nb + r) * K + kb + c4] = o;
}

// ---------------------------------------------------------------------------
// LayerNorm fp32 in -> bf16 out. One wave per row, 4 rows/block.
// ---------------------------------------------------------------------------
__global__ __launch_bounds__(256) void ln_kernel(const float* __restrict__ x,
                                                 const float* __restrict__ g,
                                                 const float* __restrict__ bta,
                                                 ushort* __restrict__ out) {
    int w = threadIdx.x >> 6;
    int lane = threadIdx.x & 63;
    size_t row = (size_t)blockIdx.x * 4 + w;
    const float* xr = x + row * DM;
    float4 v0 = *(const float4*)&xr[lane * 4];
    float4 v1 = *(const float4*)&xr[256 + lane * 4];
    float sum = v0.x + v0.y + v0.z + v0.w + v1.x + v1.y + v1.z + v1.w;
#pragma unroll
    for (int off = 32; off > 0; off >>= 1) sum += __shfl_xor(sum, off, 64);
    float mu = sum * (1.0f / 512.0f);
    float d0[8] = {v0.x - mu, v0.y - mu, v0.z - mu, v0.w - mu,
                   v1.x - mu, v1.y - mu, v1.z - mu, v1.w - mu};
    float sq = 0.0f;
#pragma unroll
    for (int i = 0; i < 8; i++) sq = fmaf(d0[i], d0[i], sq);
#pragma unroll
    for (int off = 32; off > 0; off >>= 1) sq += __shfl_xor(sq, off, 64);
    float rs = rsqrtf(sq * (1.0f / 512.0f) + 1e-3f);
    float4 g0 = *(const float4*)&g[lane * 4];
    float4 g1 = *(const float4*)&g[256 + lane * 4];
    float4 b0 = *(const float4*)&bta[lane * 4];
    float4 b1 = *(const float4*)&bta[256 + lane * 4];
    ushort* orow = out + row * DM;
    ushort4 o0, o1;
    o0.x = f2bf(fmaf(d0[0] * rs, g0.x, b0.x));
    o0.y = f2bf(fmaf(d0[1] * rs, g0.y, b0.y));
    o0.z = f2bf(fmaf(d0[2] * rs, g0.z, b0.z));
    o0.w = f2bf(fmaf(d0[3] * rs, g0.w, b0.w));
    o1.x = f2bf(fmaf(d0[4] * rs, g1.x, b1.x));
    o1.y = f2bf(fmaf(d0[5] * rs, g1.y, b1.y));
    o1.z = f2bf(fmaf(d0[6] * rs, g1.z, b1.z));
    o1.w = f2bf(fmaf(d0[7] * rs, g1.w, b1.w));
    *(ushort4*)&orow[lane * 4] = o0;
    *(ushort4*)&orow[256 + lane * 4] = o1;
}

// ---------------------------------------------------------------------------
// bf16 MFMA GEMM, BM x BN tile, BK = 32*KH, 8 waves (4x2), 512 threads,
// double-buffered LDS (r5 2-phase sync structure), T1 bijective XCD swizzle
// (requires gridDim.y % 8 == 0). Converged optimum: 3-4 blocks/CU.
// Per wave: (BM/4) x (BN/2) output = FM x FN 16x16 frags, FM=BM/64, FN=BN/32.
// MODE: 0 = bf16 store; 1 = fp32 +=; 2 = bias+relu -> bf16; 3 = bias + fp32 +=
//       5 = QKV fused: Q/K col-blocks -> bf16 store; V col-blocks (n0>=1024)
//           -> TRANSPOSED ushort4 store to aux = vT[b][c][s]
// ---------------------------------------------------------------------------
template <int BM, int BN, int KH, int MODE>
__global__ __launch_bounds__(512) void gemm_bf16(const ushort* __restrict__ A,
                                                 const ushort* __restrict__ Bt,
                                                 const float* __restrict__ bias,
                                                 void* __restrict__ Cv,
                                                 void* __restrict__ aux,
                                                 int M, int N, int K) {
    static_assert(BM % 64 == 0 && BN % 64 == 0, "tile multiple of 64");
    constexpr int FM = BM / 64;   // frags per wave, rows (wave grid 4x2)
    constexpr int FN = BN / 32;   // frags per wave, cols
    __shared__ __align__(16) ushort As[2][KH * BM * 32];
    __shared__ __align__(16) ushort Bs[2][KH * BN * 32];
    const int tid = threadIdx.x;
    const int lane = tid & 63;
    const int w = tid >> 6;                  // 0..7

    // --- XCD-locality swizzle (bijective for gridDim.y % 8 == 0) ---
    const int nx = gridDim.x;
    int wg = blockIdx.y * nx + blockIdx.x;   // hw linear dispatch id
    int xcd = wg & 7;
    int t0 = wg >> 3;
    int bx = t0 % nx;
    int by = (t0 / nx) * 8 + xcd;            // same-by blocks share xcd
    const int m0 = by * BM, n0 = bx * BN;

    const int wm = (w >> 1) * (BM / 4);      // wave row (0..3)
    const int wn = (w & 1) * (BN / 2);       // wave col (0..1)
    const int fm = lane & 15, fq = lane >> 4;

    f32x4 acc[FM][FN] = {};

    // stage K-tile [kt, kt+32*KH) into LDS buffer buf (async, wave-linear).
    // chunks16 per hf: A = BM*4, B = BN*4 (each 32-elem row = 4 x 16B).
    auto stage = [&](int buf, int kt) {
#pragma unroll
        for (int hf = 0; hf < KH; hf++) {
            constexpr int CA = BM * 4;
            if constexpr (CA >= 512) {
#pragma unroll
                for (int u = 0; u < CA / 512; u++) {
                    int chunk = u * 512 + tid;
                    int row = chunk >> 2, c = chunk & 3;
                    async16(&A[(size_t)(m0 + row) * K + kt + hf * 32 + c * 8],
                            (char*)As[buf] + hf * BM * 64 + chunk * 16);
                }
            } else {
                if (tid < CA) {
                    int chunk = tid;
                    int row = chunk >> 2, c = chunk & 3;
                    async16(&A[(size_t)(m0 + row) * K + kt + hf * 32 + c * 8],
                            (char*)As[buf] + hf * BM * 64 + chunk * 16);
                }
            }
            constexpr int CB = BN * 4;
            if constexpr (CB >= 512) {
#pragma unroll
                for (int u = 0; u < CB / 512; u++) {
                    int chunk = u * 512 + tid;
                    int row = chunk >> 2, c = chunk & 3;
                    async16(&Bt[(size_t)(n0 + row) * K + kt + hf * 32 + c * 8],
                            (char*)Bs[buf] + hf * BN * 64 + chunk * 16);
                }
            } else {
                if (tid < CB) {
                    int chunk = tid;
                    int row = chunk >> 2, c = chunk & 3;
                    async16(&Bt[(size_t)(n0 + row) * K + kt + hf * 32 + c * 8],
                            (char*)Bs[buf] + hf * BN * 64 + chunk * 16);
                }
            }
        }
    };

    stage(0, 0);
    __syncthreads();
    int cur = 0;
    for (int kt = 0; kt < K; kt += 32 * KH) {
        if (kt + 32 * KH < K) stage(cur ^ 1, kt + 32 * KH);  // prefetch next
#pragma unroll
        for (int hf = 0; hf < KH; hf++) {
            bf16x8 af[FM], bfr[FN];
#pragma unroll
            for (int i = 0; i < FM; i++)
                af[i] = *(const bf16x8*)&As[cur][hf * BM * 32 +
                                                 (wm + i * 16 + fm) * 32 + fq * 8];
#pragma unroll
            for (int j = 0; j < FN; j++)
                bfr[j] = *(const bf16x8*)&Bs[cur][hf * BN * 32 +
                                                  (wn + j * 16 + fm) * 32 + fq * 8];
#pragma unroll
            for (int i = 0; i < FM; i++)
#pragma unroll
                for (int j = 0; j < FN; j++)
                    acc[i][j] = __builtin_amdgcn_mfma_f32_16x16x32_bf16(
                        af[i], bfr[j], acc[i][j], 0, 0, 0);
        }
        __syncthreads();   // drains prefetch (vmcnt) + ds_reads (lgkmcnt)
        cur ^= 1;
    }

    if constexpr (MODE == 5) {
        if (n0 >= 1024) {
            // V col-block: transposed write to vT[b][c][s]; acc rows are 4
            // consecutive s at fixed c -> one 8B ushort4 store per frag.
            ushort* vT = (ushort*)aux;
            const int b = m0 >> 10;               // BM tiles never cross batch
            const int sl = (m0 & (SEQ - 1)) + wm + fq * 4;
#pragma unroll
            for (int i = 0; i < FM; i++) {
#pragma unroll
                for (int j = 0; j < FN; j++) {
                    int c = n0 - 1024 + wn + j * 16 + fm;
                    ushort4 o;
                    o.x = f2bf(acc[i][j][0]);
                    o.y = f2bf(acc[i][j][1]);
                    o.z = f2bf(acc[i][j][2]);
                    o.w = f2bf(acc[i][j][3]);
                    *(ushort4*)&vT[(size_t)(b * DM + c) * SEQ + sl + i * 16] = o;
                }
            }
        } else {
            // Q/K col-block: normal bf16 store
#pragma unroll
            for (int i = 0; i < FM; i++)
#pragma unroll
                for (int j = 0; j < FN; j++) {
                    int col = n0 + wn + j * 16 + fm;
#pragma unroll
                    for (int r = 0; r < 4; r++) {
                        int row = m0 + wm + i * 16 + fq * 4 + r;
                        ((ushort*)Cv)[(size_t)row * N + col] = f2bf(acc[i][j][r]);
                    }
                }
        }
        return;
    }

#pragma unroll
    for (int i = 0; i < FM; i++) {
#pragma unroll
        for (int j = 0; j < FN; j++) {
            int col = n0 + wn + j * 16 + fm;
#pragma unroll
            for (int r = 0; r < 4; r++) {
                int row = m0 + wm + i * 16 + fq * 4 + r;
                float vv = acc[i][j][r];
                if constexpr (MODE == 0) {
                    ((ushort*)Cv)[(size_t)row * N + col] = f2bf(vv);
                } else if constexpr (MODE == 1) {
                    float* C = (float*)Cv;
                    C[(size_t)row * N + col] += vv;
                } else if constexpr (MODE == 2) {
                    vv += bias[col];
                    vv = fmaxf(vv, 0.0f);
                    ((ushort*)Cv)[(size_t)row * N + col] = f2bf(vv);
                } else {
                    float* C = (float*)Cv;
                    C[(size_t)row * N + col] += vv + bias[col];
                }
            }
        }
    }
}

// ---------------------------------------------------------------------------
// Flash attention, S^T formulation. 512 thr = 8 waves, one (b,h), 128 q rows
// (16/wave, q = lane&15). Double-buffered K/V LDS -> ONE barrier per tile;
// in-register monotone mask; defer-max (T13), exp2 softmax, setprio (T5),
// length-based tile skip.
// r18: XCD-locality grid — x = b*NH+h (fastest), y = qtile. All 8 q-blocks
// sharing one (b,h)'s K/V have linear IDs == h (mod 8) -> same XCD; each
// XCD's K/V working set is 8 pairs x 256KB = 2MB <= 4MB L2, so K/V is
// fetched from HBM once and served from L2 to the other 7 blocks
// (same mechanism as the r3 GEMM swizzle: FETCH 140->33MB there).
// ---------------------------------------------------------------------------
__global__ __launch_bounds__(512) void attn_mfma(const ushort* __restrict__ QKV,
                                                 const ushort* __restrict__ Vt,
                                                 const int* __restrict__ mask,
                                                 ushort* __restrict__ O) {
    __shared__ __align__(16) ushort Kt[2][64 * 64];
    __shared__ __align__(16) ushort Vs[2][64 * 64];
    __shared__ __align__(16) ushort ps[8][16 * 72];  // per-wave P^T [q][key], stride 72
    __shared__ int lensh[8];

    const int tid = threadIdx.x, lane = tid & 63, w = tid >> 6;
    const int b = blockIdx.x >> 3, h = blockIdx.x & 7;   // x = b*NH+h (fastest)
    const int q0 = blockIdx.y * 128 + w * 16;
    const int fm = lane & 15, fq = lane >> 4;
    ushort* pw = &ps[w][0];
    const float L2E = 1.44269504f;

    // ---- sequence length for batch b (mask is monotone 1s then 0s) ----
    int part = mask[b * SEQ + tid] + mask[b * SEQ + 512 + tid];
#pragma unroll
    for (int off = 32; off > 0; off >>= 1) part += __shfl_xor(part, off, 64);
    if (lane == 0) lensh[w] = part;

    // Q as B-fragment, pre-scaled by 0.125 (exact in bf16: exponent shift)
    bf16x8 qf[2];
#pragma unroll
    for (int kk = 0; kk < 2; kk++) {
        bf16x8 t = *(const bf16x8*)&QKV[(size_t)(b * SEQ + q0 + fm) * QKVD + h * HDIM +
                                        kk * 32 + fq * 8];
#pragma unroll
        for (int j = 0; j < 8; j++) {
            union { float f; unsigned u; } vv;
            vv.u = ((unsigned)(ushort)t[j]) << 16;
            vv.f *= 0.125f;
            t[j] = (short)(ushort)(vv.u >> 16);   // exact: mantissa unchanged
        }
        qf[kk] = t;
    }

    // per-thread staging indices: 512 thr x 16B = one full 64x64 bf16 tile
    const int r0 = tid >> 3, c0 = tid & 7;
    const int dk0 = (r0 * 8 + (c0 ^ (r0 & 7))) * 16;

    auto gK = [&](int j0) {
        return (const uint4*)&QKV[(size_t)(b * SEQ + j0 + r0) * QKVD + 512 +
                                  h * HDIM + c0 * 8];
    };
    auto gV = [&](int j0) {
        return (const uint4*)&Vt[(size_t)((b * NH + h) * HDIM + r0) * SEQ + j0 + c0 * 8];
    };

    // ---- prologue: tile 0 into regs ----
    uint4 kreg = *gK(0);
    uint4 vreg = *gV(0);

    f32x4 oacc[4] = {};   // O^T: col = q (fm), rows dim = nt*16 + fq*4 + r
    float mrow = -INFINITY, lrow = 0.0f;
    int len = 0;
    int jmax = SEQ;       // provisional; fixed after first barrier

    for (int j0 = 0; j0 < jmax; j0 += 64) {
        const int buf = (j0 >> 6) & 1;
        // write tile j0 (in regs) to its LDS buffer, then the ONE barrier
        *(uint4*)((char*)Kt[buf] + dk0) = kreg;
        *(uint4*)((char*)Vs[buf] + dk0) = vreg;
        __syncthreads();
        if (j0 == 0) {    // lensh visible now (written pre-loop, pre-barrier)
            len = lensh[0] + lensh[1] + lensh[2] + lensh[3] +
                  lensh[4] + lensh[5] + lensh[6] + lensh[7];
            jmax = (len + 63) & ~63;   // >= 512 always (len >= SEQ/2)
        }
        const bool has_next = (j0 + 64 < jmax);
        if (has_next) {   // issue next-tile loads; latency hides under compute
            kreg = *gK(j0 + 64);
            vreg = *gV(j0 + 64);
        }

        // ---- S^T = K Q^T : lane holds q-col fm, keys nt*16 + fq*4 + r ----
        f32x4 sc[4] = {};
        __builtin_amdgcn_s_setprio(1);
#pragma unroll
        for (int nt = 0; nt < 4; nt++) {
            int key = nt * 16 + fm;
#pragma unroll
            for (int kk = 0; kk < 2; kk++) {
                bf16x8 kf = *(const bf16x8*)((char*)Kt[buf] +
                            (key * 8 + ((kk * 4 + fq) ^ (key & 7))) * 16);
                sc[nt] = __builtin_amdgcn_mfma_f32_16x16x32_bf16(kf, qf[kk], sc[nt], 0, 0, 0);
            }
        }
        __builtin_amdgcn_s_setprio(0);

        // ---- online softmax (defer-max, THR=8) over the lane's 16 keys ----
        float mx = -INFINITY;
#pragma unroll
        for (int nt = 0; nt < 4; nt++)
#pragma unroll
            for (int r = 0; r < 4; r++) mx = fmaxf(mx, sc[nt][r]);
        mx = fmaxf(mx, __shfl_xor(mx, 16));
        mx = fmaxf(mx, __shfl_xor(mx, 32));
        if (!__all(mx - mrow <= 8.0f)) {
            float mn = fmaxf(mrow, mx);
            float alpha = __expf(mrow - mn);
            mrow = mn;
            lrow *= alpha;
#pragma unroll
            for (int nt = 0; nt < 4; nt++)
#pragma unroll
                for (int r = 0; r < 4; r++) oacc[nt][r] *= alpha;
        }

        const float nm2 = -mrow * L2E;   // exp(s-m) == exp2(s*L2E - m*L2E)
        float sv[4][4];
        float ls = 0.0f;
        if (j0 + 64 <= len) {            // full tile: all keys valid (uniform)
#pragma unroll
            for (int nt = 0; nt < 4; nt++)
#pragma unroll
                for (int r = 0; r < 4; r++) {
                    float p = exp2f(fmaf(sc[nt][r], L2E, nm2));
                    sv[nt][r] = p;
                    ls += p;
                }
        } else {                          // tail tile: in-register mask
#pragma unroll
            for (int nt = 0; nt < 4; nt++)
#pragma unroll
                for (int r = 0; r < 4; r++) {
                    int key = j0 + nt * 16 + fq * 4 + r;
                    float p = (key < len) ? exp2f(fmaf(sc[nt][r], L2E, nm2)) : 0.0f;
                    sv[nt][r] = p;
                    ls += p;
                }
        }
        ls += __shfl_xor(ls, 16);
        ls += __shfl_xor(ls, 32);
        lrow += ls;

        // ---- P^T to per-wave LDS: pw[q=fm][key], trunc-to-bf16 packed ----
#pragma unroll
        for (int nt = 0; nt < 4; nt++) {
            union { float f; unsigned u; } a0, a1, a2, a3;
            a0.f = sv[nt][0]; a1.f = sv[nt][1]; a2.f = sv[nt][2]; a3.f = sv[nt][3];
            unsigned d0 = (a0.u >> 16) | (a1.u & 0xFFFF0000u);
            unsigned d1 = (a2.u >> 16) | (a3.u & 0xFFFF0000u);
            *(uint2*)&pw[fm * 72 + nt * 16 + fq * 4] = make_uint2(d0, d1);
        }

        // ---- O^T += V^T P^T ----
        __builtin_amdgcn_s_setprio(1);
#pragma unroll
        for (int kk = 0; kk < 2; kk++) {
            bf16x8 pf = *(const bf16x8*)&pw[fm * 72 + kk * 32 + fq * 8];
#pragma unroll
            for (int nt = 0; nt < 4; nt++) {
                int dim = nt * 16 + fm;
                bf16x8 vf = *(const bf16x8*)((char*)Vs[buf] +
                            (dim * 8 + ((kk * 4 + fq) ^ (dim & 7))) * 16);
                oacc[nt] = __builtin_amdgcn_mfma_f32_16x16x32_bf16(vf, pf, oacc[nt], 0, 0, 0);
            }
        }
        __builtin_amdgcn_s_setprio(0);
        // no trailing barrier: buf is next written at j0+128, after the
        // barrier at j0+64 which orders all reads of buf before that write
    }

    float inv = 1.0f / lrow;
#pragma unroll
    for (int nt = 0; nt < 4; nt++) {
        ushort4 o;
        o.x = f2bf(oacc[nt][0] * inv);
        o.y = f2bf(oacc[nt][1] * inv);
        o.z = f2bf(oacc[nt][2] * inv);
        o.w = f2bf(oacc[nt][3] * inv);
        *(ushort4*)&O[(size_t)(b * SEQ + q0 + fm) * DM + h * HDIM + nt * 16 + fq * 4] = o;
    }
}

// ---------------------------------------------------------------------------
extern "C" void kernel_launch(void* const* d_in, const int* in_sizes, int n_in,
                              void* d_out, int out_size, void* d_ws, size_t ws_size,
                              hipStream_t stream) {
    const float* x_in = (const float*)d_in[0];
    const int* mask   = (const int*)d_in[1];
    const float* Wq   = (const float*)d_in[2];
    const float* Wk   = (const float*)d_in[3];
    const float* Wv   = (const float*)d_in[4];
    const float* Wo   = (const float*)d_in[5];
    const float* ln1g = (const float*)d_in[6];
    const float* ln1b = (const float*)d_in[7];
    const float* ln2g = (const float*)d_in[8];
    const float* ln2b = (const float*)d_in[9];
    const float* W1   = (const float*)d_in[10];
    const float* b1   = (const float*)d_in[11];
    const float* W2   = (const float*)d_in[12];
    const float* b2   = (const float*)d_in[13];

    float* x = (float*)d_out;  // fp32 residual stream
    ushort* wsb = (ushort*)d_ws;
    const size_t U = 1048576;
    ushort* WqkvT = wsb;            // [L][1536][512]  (3U)
    ushort* WoT   = wsb + 3 * U;    // [L][512][512]   (1U)
    ushort* W1T   = wsb + 4 * U;    // [L][2048][512]  (4U)
    ushort* W2T   = wsb + 8 * U;    // [L][512][2048]  (4U)
    ushort* hb    = wsb + 12 * U;   // bf16 [8192][512]
    ushort* qkv   = wsb + 16 * U;   // bf16 [8192][1536] (12U; V region dead)
    ushort* ob    = wsb + 28 * U;   // bf16 [8192][512]
    ushort* vTb   = wsb + 32 * U;   // bf16 [8][512][1024]
    ushort* f1b   = qkv;            // 16U alias (qkv+ob), dead during FFN

    // Merged weight convert+transpose (graph-safe: every launch)
    wtrans_all<<<dim3(3072, 1, 4), 256, 0, stream>>>(Wq, Wk, Wv, Wo, W1, W2,
                                                     WqkvT, WoT, W1T, W2T);

    add_pos_kernel<<<(NTOK * DM / 4) / 256, 256, 0, stream>>>(x_in, x);

    dim3 gQKV(QKVD / 128, NTOK / 128);   // (12, 64)  = 768 blocks, 3/CU
    dim3 gProj(DM / 64, NTOK / 64);      // (8, 128)  = 1024 blocks, 4/CU
    dim3 gFF1(DFF / 128, NTOK / 128);    // (16, 64)  = 1024 blocks, 4/CU
    dim3 gFF2(DM / 64, NTOK / 64);       // (8, 128)  = 1024 blocks, 4/CU
    dim3 gAttn(NB * NH, SEQ / 128);      // (64, 8): x=(b,h) fastest -> XCD-local K/V

    for (int l = 0; l < NLAYER; l++) {
        const size_t wOff   = (size_t)l * 262144;
        const size_t wqkvOff= (size_t)l * 786432;
        const size_t w1Off  = (size_t)l * 1048576;

        ln_kernel<<<NTOK / 4, 256, 0, stream>>>(x, ln1g + l * DM, ln1b + l * DM, hb);
        gemm_bf16<128, 128, 1, 5><<<gQKV, 512, 0, stream>>>(hb, WqkvT + wqkvOff, nullptr,
                                                            qkv, vTb, NTOK, QKVD, DM);
        attn_mfma<<<gAttn, 512, 0, stream>>>(qkv, vTb, mask, ob);
        gemm_bf16<64, 64, 2, 1><<<gProj, 512, 0, stream>>>(ob, WoT + wOff, nullptr, x,
                                                           nullptr, NTOK, DM, DM);
        ln_kernel<<<NTOK / 4, 256, 0, stream>>>(x, ln2g + l * DM, ln2b + l * DM, hb);
        gemm_bf16<128, 128, 1, 2><<<gFF1, 512, 0, stream>>>(hb, W1T + w1Off,
                                                            b1 + (size_t)l * DFF, f1b,
                                                            nullptr, NTOK, DFF, DM);
        gemm_bf16<64, 64, 2, 3><<<gFF2, 512, 0, stream>>>(f1b, W2T + w1Off,
                                                          b2 + (size_t)l * DM, x,
                                                          nullptr, NTOK, DM, DFF);
    }
}